// Round 11
// baseline (103.918 us; speedup 1.0000x reference)
//
#include <hip/hip_runtime.h>

typedef __attribute__((ext_vector_type(8)))  __bf16 bvec8;
typedef __attribute__((ext_vector_type(4)))  __bf16 bvec4;
typedef __attribute__((ext_vector_type(16))) float  fvec16;
typedef __attribute__((ext_vector_type(8)))  short  svec8;

// ---- pack W[l][j][k][i] fp32 -> Wp bf16, wave-contiguous 32x32x16 frags ----
// unit u: lane=u&63, f=(u>>6)&7 (am=f&3, h=f>>2), wi=(u>>9)&3, t=u>>11 (0..35)
// content: i=(wi*4+am)*32+(lane&31), K=(2t+h)*16+(lane>>5)*8+e ; K=jk*128+l
__global__ __launch_bounds__(256) void pack_w(const float* __restrict__ W,
                                              __bf16* __restrict__ Wp) {
    int u = blockIdx.x * 256 + threadIdx.x;
    if (u >= 73728) return;                   // 36 t * 4 wi * 8 f * 64 lanes
    int lane = u & 63;
    int f    = (u >> 6) & 7;
    int wi   = (u >> 9) & 3;
    int t    = u >> 11;
    int am = f & 3, h = f >> 2;
    int i  = ((wi * 4 + am) << 5) + (lane & 31);
    int K0 = ((2 * t + h) << 4) + ((lane >> 5) << 3);
    bvec8 o;
#pragma unroll
    for (int e = 0; e < 8; ++e) {
        int K  = K0 + e;
        int jk = K >> 7;
        int l  = K & 127;
        int j  = (jk * 11) >> 5;              // jk/3 for jk<9
        int k  = jk - 3 * j;
        o[e] = (__bf16)W[((l * 9 + j * 3 + k) << 9) + i];
    }
    *(bvec8*)&Wp[(size_t)u * 8] = o;
}

// ---- main: block = 2 batches x 512 i x 64 s, 512 thr = 8 waves ----
// wave (wi = wid&3, ws = wid>>2): am4 (128 i) x sn1 (32 s) x bb2 -> acc[4][2].
// ys dedup (per batch, 78 rows x 128 l):
//   rows 0..62: t=n+j: [1<=t<=7]*xA[t-1,w] + xB[(t+5)%7,w]
//   63..69: xA[0,w] (n=1,j=0) ; 70..76: xA[1,w] (n=0,j=2) ; 77: zeros
// 16B-unit swizzle u^=(row&15).
// K-loop: barrier-free; W reg-dbuf dist-2 (aE/aO); bf reg-dbuf dist-1 (bfA/bfB);
// per-block K-START ROTATION (off = bx%9) to decorrelate W L2 traffic.
__global__ __launch_bounds__(512, 2) void conv_mfma(
    const float* __restrict__ x, const __bf16* __restrict__ Wp,
    float* __restrict__ out)
{
    __shared__ __align__(16) char smem[65024];
    __bf16* xs = (__bf16*)smem;               // 25088 B (build)
    __bf16* ys = (__bf16*)(smem + 25088);     // 39936 B (2 x 78 x 256 B)
    float*  T  = (float*)smem;                // 53248 B (epilogue, stride 52)

    const int tid  = threadIdx.x;
    const int lane = tid & 63;
    const int l31  = lane & 31;
    const int ls5  = lane >> 5;
    const int wid  = tid >> 6;
    const int wi   = wid & 3;                 // i-group (128 i)
    const int ws   = wid >> 2;                // s-tile (32 s)
    const int bx   = blockIdx.x;
    const int b0   = bx * 2;
    const int off  = bx % 9;                  // K-rotation offset

    const float* xb  = x + (size_t)b0 * 12544;
    const char*  WpB = (const char*)Wp;

    // ---- W prologue: rotated tiles 4*off, 4*off+1 (land during build) ----
    bvec8 aE[4][2], aO[4][2];
    {
        const char* gE = WpB + (size_t)((4 * off + 0) * 4 + wi) * 8192 + ((size_t)lane << 4);
        const char* gO = WpB + (size_t)((4 * off + 1) * 4 + wi) * 8192 + ((size_t)lane << 4);
#pragma unroll
        for (int am = 0; am < 4; ++am)
#pragma unroll
            for (int h = 0; h < 2; ++h) {
                aE[am][h] = *(const bvec8*)(gE + ((h * 4 + am) << 10));
                aO[am][h] = *(const bvec8*)(gO + ((h * 4 + am) << 10));
            }
    }

    // ---- build ys for both batches ----
#pragma unroll
    for (int bb = 0; bb < 2; ++bb) {
        for (int it = 0; it < 7; ++it) {
            int e4 = it * 512 + tid;
            if (e4 < 3136) {
                const float4 v = ((const float4*)(xb + bb * 12544))[e4];
                bvec4 pk = { (__bf16)v.x, (__bf16)v.y, (__bf16)v.z, (__bf16)v.w };
                *(bvec4*)&xs[e4 * 4] = pk;
            }
        }
        __syncthreads();
        for (int it = 0; it < 3; ++it) {
            int up = it * 512 + tid;
            if (up < 1248) {
                int row  = up >> 4;
                int useg = up & 15;
                int l0   = useg * 8;
                bvec8 ov;
                if (row == 77) {
                    ov = __builtin_bit_cast(bvec8, (svec8)0);
                } else if (row < 63) {
                    int t = row / 7, w = row - t * 7;
                    int tb = t + 5; if (tb >= 7) tb -= 7;
                    int cB = tb * 7 + w;
                    bool mA = (t >= 1) && (t <= 7);
                    int cA = mA ? (t - 1) * 7 + w : 0;
#pragma unroll
                    for (int d = 0; d < 8; ++d) {
                        float fa = mA ? (float)xs[(l0 + d) * 49 + cA] : 0.f;
                        float fb = (float)xs[(128 + l0 + d) * 49 + cB];
                        ov[d] = (__bf16)(fa + fb);
                    }
                } else if (row < 70) {
                    int w = row - 63;
#pragma unroll
                    for (int d = 0; d < 8; ++d) ov[d] = xs[(l0 + d) * 49 + w];
                } else {
                    int w = row - 70;
#pragma unroll
                    for (int d = 0; d < 8; ++d) ov[d] = xs[(l0 + d) * 49 + 7 + w];
                }
                *(bvec8*)&ys[((bb * 78 + row) << 7) + ((useg ^ (row & 15)) << 3)] = ov;
            }
        }
        __syncthreads();
    }

    // ---- per-lane column geometry: s = ws*32 + l31 ----
    const int s_ = ws * 32 + l31;
    const int sc = (s_ < 49) ? s_ : 48;
    const int nq = sc / 7;
    const int oo = sc - nq * 7;

    fvec16 acc[4][2];
#pragma unroll
    for (int am = 0; am < 4; ++am)
#pragma unroll
        for (int bb = 0; bb < 2; ++bb)
#pragma unroll
            for (int r = 0; r < 16; ++r) acc[am][bb][r] = 0.f;

#define GEO(JK, ROWE, RX) {                                                   \
        int j_ = ((JK) * 11) >> 5; int k_ = (JK) - 3 * j_;                    \
        int tw_ = oo + k_ + 5; int w_ = tw_ >= 7 ? tw_ - 7 : tw_;             \
        int row_ = (nq + j_) * 7 + w_;                                        \
        if (nq == 1 && j_ == 0) row_ = 63 + w_;                               \
        if (nq == 0 && j_ == 2) row_ = 70 + w_;                               \
        if ((k_ == 0 && oo == 0) || (k_ == 2 && oo == 6)) row_ = 77;          \
        ROWE = row_ << 7; RX = row_ & 15; }

#define READF(DST, P, ROWE, RX) {                                             \
        _Pragma("unroll")                                                     \
        for (int h_ = 0; h_ < 2; ++h_) {                                      \
            int u_ = ((P) * 4 + h_ * 2 + ls5) ^ (RX);                         \
            DST[0][h_] = *(const bvec8*)&ys[(ROWE) + (u_ << 3)];              \
            DST[1][h_] = *(const bvec8*)&ys[9984 + (ROWE) + (u_ << 3)]; } }

#define MFMA16(AW, BF) {                                                      \
        __builtin_amdgcn_s_setprio(1);                                        \
        _Pragma("unroll")                                                     \
        for (int h_ = 0; h_ < 2; ++h_)                                        \
        _Pragma("unroll")                                                     \
        for (int am_ = 0; am_ < 4; ++am_)                                     \
        _Pragma("unroll")                                                     \
        for (int bb_ = 0; bb_ < 2; ++bb_)                                     \
            acc[am_][bb_] = __builtin_amdgcn_mfma_f32_32x32x16_bf16(          \
                AW[am_][h_], BF[bb_][h_], acc[am_][bb_], 0, 0, 0);            \
        __builtin_amdgcn_s_setprio(0); }

#define PREFW(AW, TT) {                                                       \
        const char* gp_ = WpB + (size_t)((TT) * 4 + wi) * 8192                \
                          + ((size_t)lane << 4);                              \
        _Pragma("unroll")                                                     \
        for (int am_ = 0; am_ < 4; ++am_)                                     \
        _Pragma("unroll")                                                     \
        for (int h_ = 0; h_ < 2; ++h_)                                        \
            AW[am_][h_] = *(const bvec8*)(gp_ + ((h_ * 4 + am_) << 10)); }

    // ---- K-loop: 9 rotated jk-groups x 4 steps, barrier-free, dual reg-dbuf ----
    int rowE, rx, rowEn, rxn;
    int jkr = off;
    GEO(jkr, rowE, rx);
    bvec8 bfA[2][2], bfB[2][2];
    READF(bfA, 0, rowE, rx);

    for (int idx = 0; idx < 9; ++idx) {
        const int t0 = jkr * 4;
        int jkn = jkr + 1; if (jkn == 9) jkn = 0;
        const bool last = (idx == 8);
        // p0: aE holds tile t0
        READF(bfB, 1, rowE, rx);
        MFMA16(aE, bfA);
        PREFW(aE, t0 + 2);
        // p1
        READF(bfA, 2, rowE, rx);
        MFMA16(aO, bfB);
        PREFW(aO, t0 + 3);
        // p2
        { int g = last ? jkr : jkn; GEO(g, rowEn, rxn); }   // last: dummy
        READF(bfB, 3, rowE, rx);
        MFMA16(aE, bfA);
        if (!last) PREFW(aE, jkn * 4 + 0);
        // p3: read p0 of next jk with next geometry
        READF(bfA, 0, rowEn, rxn);
        MFMA16(aO, bfB);
        if (!last) PREFW(aO, jkn * 4 + 1);
        rowE = rowEn; rx = rxn;
        jkr = jkn;
    }

#undef GEO
#undef READF
#undef MFMA16
#undef PREFW

    // ---- epilogue: acc -> T (LDS) -> linear coalesced stores ----
    // D: row=(r&3)+8*(r>>2)+4*ls5 -> i ; col=l31 -> s
#pragma unroll
    for (int pass = 0; pass < 4; ++pass) {
        const int bb = pass >> 1, ih = pass & 1;
        __syncthreads();
        if ((wi >> 1) == ih && s_ < 49) {
            const int irb = (wi & 1) * 128 + 4 * ls5;
#pragma unroll
            for (int am = 0; am < 4; ++am)
#pragma unroll
                for (int r = 0; r < 16; ++r) {
                    int ir = irb + am * 32 + (r & 3) + 8 * (r >> 2);
                    T[ir * 52 + s_] = acc[am][bb][r];
                }
        }
        __syncthreads();
        const size_t ob = (size_t)(b0 + bb) * 25088 + (size_t)ih * 12544;
        for (int it = 0; it < 25; ++it) {
            int idx = it * 512 + tid;
            if (idx < 12544) {
                int ir = idx / 49;
                int s  = idx - ir * 49;
                out[ob + idx] = T[ir * 52 + s];
            }
        }
    }
}

extern "C" void kernel_launch(void* const* d_in, const int* in_sizes, int n_in,
                              void* d_out, int out_size, void* d_ws, size_t ws_size,
                              hipStream_t stream) {
    const float* x = (const float*)d_in[0];   // (1024,256,7,7)
    const float* W = (const float*)d_in[1];   // (128,3,3,512)
    float* out = (float*)d_out;               // (1024,512,7,7)
    __bf16* Wp = (__bf16*)d_ws;               // 73728*8 bf16 = 1.18 MB
    (void)in_sizes; (void)n_in; (void)out_size; (void)ws_size;

    hipLaunchKernelGGL(pack_w, dim3(288), dim3(256), 0, stream, W, Wp);
    hipLaunchKernelGGL(conv_mfma, dim3(512), dim3(512), 0, stream, x, Wp, out);
}

// Round 12
// 94.551 us; speedup vs baseline: 1.0991x; 1.0991x over previous
//
#include <hip/hip_runtime.h>

typedef __attribute__((ext_vector_type(8)))  __bf16 bvec8;
typedef __attribute__((ext_vector_type(4)))  __bf16 bvec4;
typedef __attribute__((ext_vector_type(16))) float  fvec16;
typedef __attribute__((ext_vector_type(8)))  short  svec8;

// ---- pack W[l][j][k][i] fp32 -> Wp bf16, per-wave-unique 32x32x16 frags ----
// unit u: lane=u&63, f=(u>>6)&3 (am=f&1,h=f>>1), wd=(u>>8)&7, t=u>>11 (0..35)
// content: i = wd*64 + am*32 + (lane&31) ; K = (2t+h)*16 + (lane>>5)*8 + e
__global__ __launch_bounds__(256) void pack_w(const float* __restrict__ W,
                                              __bf16* __restrict__ Wp) {
    int u = blockIdx.x * 256 + threadIdx.x;
    if (u >= 73728) return;                   // 36 t * 8 wd * 4 f * 64 lanes
    int lane = u & 63;
    int f    = (u >> 6) & 3;
    int wd   = (u >> 8) & 7;
    int t    = u >> 11;
    int am = f & 1, h = f >> 1;
    int i  = (wd << 6) + (am << 5) + (lane & 31);
    int K0 = ((2 * t + h) << 4) + ((lane >> 5) << 3);
    bvec8 o;
#pragma unroll
    for (int e = 0; e < 8; ++e) {
        int K  = K0 + e;
        int jk = K >> 7;
        int l  = K & 127;
        int j  = (jk * 11) >> 5;              // jk/3 for jk<9
        int k  = jk - 3 * j;
        o[e] = (__bf16)W[((l * 9 + j * 3 + k) << 9) + i];
    }
    *(bvec8*)&Wp[(size_t)u * 8] = o;
}

// ---- main: block = 2 batches x 512 i x 49 s, 512 thr = 8 waves ----
// wave wd owns i in [wd*64, wd*64+64): am2 x sn2 x bb2 -> acc[2][2][2] (128 AGPR).
// W frags UNIQUE per wave (no s-twin duplication): 4 global b128 loads/step/wave.
// ys dedup (per batch, 78 rows x 128 l), 16B-unit swizzle u^=(row&15); row 77 zeros.
// K-loop: barrier-free; W reg-dbuf dist-2 (aE/aO); bf reg-dbuf dist-1 (bfA/bfB).
__global__ __launch_bounds__(512, 2) void conv_mfma(
    const float* __restrict__ x, const __bf16* __restrict__ Wp,
    float* __restrict__ out)
{
    extern __shared__ __align__(16) char smem[];
    __bf16* xs = (__bf16*)smem;               // 2 x 12544 bf16 = 50176 B (build)
    __bf16* ys = (__bf16*)(smem + 50176);     // 2 x 78 x 128 bf16 = 39936 B

    const int tid  = threadIdx.x;
    const int lane = tid & 63;
    const int l31  = lane & 31;
    const int ls5  = lane >> 5;
    const int wd   = tid >> 6;                // wave 0..7: i-slice [wd*64, wd*64+64)
    const int b0   = blockIdx.x * 2;

    const float* xb  = x + (size_t)b0 * 12544;
    const char*  WpB = (const char*)Wp;
    const int wbase  = wd * 4096 + lane * 16; // wave's byte base within a 32 KB tile

    // ---- W prologue: tiles 0,1 into regs (land during build) ----
    bvec8 aE[2][2], aO[2][2];
#pragma unroll
    for (int am = 0; am < 2; ++am)
#pragma unroll
        for (int h = 0; h < 2; ++h) {
            aE[am][h] = *(const bvec8*)(WpB + wbase + ((h * 2 + am) << 10));
            aO[am][h] = *(const bvec8*)(WpB + 32768 + wbase + ((h * 2 + am) << 10));
        }

    // ---- build pass 1: both batches x (f32) -> xs (bf16), one coalesced sweep ----
    for (int it = 0; it < 13; ++it) {
        int e4 = it * 512 + tid;
        if (e4 < 6272) {
            const float4 v = ((const float4*)xb)[e4];
            bvec4 pk = { (__bf16)v.x, (__bf16)v.y, (__bf16)v.z, (__bf16)v.w };
            *(bvec4*)&xs[e4 * 4] = pk;
        }
    }
    __syncthreads();

    // ---- build pass 2: write-once dedup ys, both batches (2496 units) ----
    for (int it = 0; it < 5; ++it) {
        int up = it * 512 + tid;
        if (up < 2496) {
            int bb   = up >= 1248;
            int rem  = up - bb * 1248;
            int row  = rem >> 4;
            int useg = rem & 15;
            int l0   = useg * 8;
            const __bf16* xsb = xs + bb * 12544;
            bvec8 ov;
            if (row == 77) {
                ov = __builtin_bit_cast(bvec8, (svec8)0);
            } else if (row < 63) {
                int t = row / 7, w = row - t * 7;
                int tb = t + 5; if (tb >= 7) tb -= 7;
                int cB = tb * 7 + w;
                bool mA = (t >= 1) && (t <= 7);
                int cA = mA ? (t - 1) * 7 + w : 0;
#pragma unroll
                for (int d = 0; d < 8; ++d) {
                    float fa = mA ? (float)xsb[(l0 + d) * 49 + cA] : 0.f;
                    float fb = (float)xsb[(128 + l0 + d) * 49 + cB];
                    ov[d] = (__bf16)(fa + fb);
                }
            } else if (row < 70) {
                int w = row - 63;
#pragma unroll
                for (int d = 0; d < 8; ++d) ov[d] = xsb[(l0 + d) * 49 + w];
            } else {
                int w = row - 70;
#pragma unroll
                for (int d = 0; d < 8; ++d) ov[d] = xsb[(l0 + d) * 49 + 7 + w];
            }
            *(bvec8*)&ys[((bb * 78 + row) << 7) + ((useg ^ (row & 15)) << 3)] = ov;
        }
    }

    // ---- per-lane column geometry: s = sn*32 + l31, both s-tiles per wave ----
    int nq[2], oo[2];
#pragma unroll
    for (int sn = 0; sn < 2; ++sn) {
        int s = sn * 32 + l31;
        int sc = (s < 49) ? s : 48;
        nq[sn] = sc / 7;
        oo[sn] = sc - nq[sn] * 7;
    }

    fvec16 acc[2][2][2];
#pragma unroll
    for (int am = 0; am < 2; ++am)
#pragma unroll
        for (int sn = 0; sn < 2; ++sn)
#pragma unroll
            for (int bb = 0; bb < 2; ++bb)
#pragma unroll
                for (int r = 0; r < 16; ++r) acc[am][sn][bb][r] = 0.f;

    __syncthreads();   // ys complete; no further barriers

#define GEO(JK, ROWE, RX) {                                                   \
        int j_ = ((JK) * 11) >> 5; int k_ = (JK) - 3 * j_;                    \
        _Pragma("unroll")                                                     \
        for (int sn_ = 0; sn_ < 2; ++sn_) {                                   \
            int tw_ = oo[sn_] + k_ + 5; int w_ = tw_ >= 7 ? tw_ - 7 : tw_;    \
            int row_ = (nq[sn_] + j_) * 7 + w_;                               \
            if (nq[sn_] == 1 && j_ == 0) row_ = 63 + w_;                      \
            if (nq[sn_] == 0 && j_ == 2) row_ = 70 + w_;                      \
            if ((k_ == 0 && oo[sn_] == 0) || (k_ == 2 && oo[sn_] == 6))       \
                row_ = 77;                                                    \
            ROWE[sn_] = row_ << 7; RX[sn_] = row_ & 15; } }

#define READF(DST, P, ROWE, RX) {                                             \
        _Pragma("unroll")                                                     \
        for (int sn_ = 0; sn_ < 2; ++sn_)                                     \
        _Pragma("unroll")                                                     \
        for (int h_ = 0; h_ < 2; ++h_) {                                      \
            int u_ = ((P) * 4 + h_ * 2 + ls5) ^ RX[sn_];                      \
            DST[sn_][0][h_] = *(const bvec8*)&ys[ROWE[sn_] + (u_ << 3)];      \
            DST[sn_][1][h_] = *(const bvec8*)&ys[9984 + ROWE[sn_] + (u_ << 3)]; } }

#define MFMA16(AW, BF) {                                                      \
        __builtin_amdgcn_s_setprio(1);                                        \
        _Pragma("unroll")                                                     \
        for (int h_ = 0; h_ < 2; ++h_)                                        \
        _Pragma("unroll")                                                     \
        for (int am_ = 0; am_ < 2; ++am_)                                     \
        _Pragma("unroll")                                                     \
        for (int sn_ = 0; sn_ < 2; ++sn_)                                     \
        _Pragma("unroll")                                                     \
        for (int bb_ = 0; bb_ < 2; ++bb_)                                     \
            acc[am_][sn_][bb_] = __builtin_amdgcn_mfma_f32_32x32x16_bf16(     \
                AW[am_][h_], BF[sn_][bb_][h_], acc[am_][sn_][bb_], 0, 0, 0);  \
        __builtin_amdgcn_s_setprio(0); }

#define PREFW(AW, TT) {                                                       \
        const char* gp_ = WpB + ((size_t)(TT) << 15) + wbase;                 \
        _Pragma("unroll")                                                     \
        for (int am_ = 0; am_ < 2; ++am_)                                     \
        _Pragma("unroll")                                                     \
        for (int h_ = 0; h_ < 2; ++h_)                                        \
            AW[am_][h_] = *(const bvec8*)(gp_ + ((h_ * 2 + am_) << 10)); }

    // ---- K-loop: 9 jk x 4 steps, barrier-free, dual reg-dbuf ----
    int rowE[2], rx[2], rowEn[2], rxn[2];
    GEO(0, rowE, rx);
    bvec8 bfA[2][2][2], bfB[2][2][2];
    READF(bfA, 0, rowE, rx);

    for (int jk = 0; jk < 9; ++jk) {
        const int t0 = jk * 4;
        // p0: aE holds tile t0
        READF(bfB, 1, rowE, rx);
        MFMA16(aE, bfA);
        PREFW(aE, t0 + 2);
        // p1
        READF(bfA, 2, rowE, rx);
        MFMA16(aO, bfB);
        PREFW(aO, t0 + 3);
        // p2
        { int jn = jk < 8 ? jk + 1 : 8; GEO(jn, rowEn, rxn); }
        READF(bfB, 3, rowE, rx);
        MFMA16(aE, bfA);
        if (jk < 8) PREFW(aE, t0 + 4);
        // p3: read p0 of next jk with next geometry
        READF(bfA, 0, rowEn, rxn);
        MFMA16(aO, bfB);
        if (jk < 8) PREFW(aO, t0 + 5);
#pragma unroll
        for (int sn = 0; sn < 2; ++sn) { rowE[sn] = rowEn[sn]; rx[sn] = rxn[sn]; }
    }

#undef GEO
#undef READF
#undef MFMA16
#undef PREFW

    // ---- epilogue: direct stores. D row=(r&3)+8*(r>>2)+4*ls5 -> i ; col=l31 -> s ----
#pragma unroll
    for (int am = 0; am < 2; ++am) {
        const int i0 = wd * 64 + am * 32 + 4 * ls5;
#pragma unroll
        for (int sn = 0; sn < 2; ++sn) {
            if (sn == 1 && l31 >= 17) continue;   // s >= 49
            const int s = sn * 32 + l31;
#pragma unroll
            for (int bb = 0; bb < 2; ++bb) {
                const size_t ob = (size_t)(b0 + bb) * 25088;
#pragma unroll
                for (int r = 0; r < 16; ++r) {
                    int i = i0 + (r & 3) + 8 * (r >> 2);
                    out[ob + (size_t)i * 49 + s] = acc[am][sn][bb][r];
                }
            }
        }
    }
}

extern "C" void kernel_launch(void* const* d_in, const int* in_sizes, int n_in,
                              void* d_out, int out_size, void* d_ws, size_t ws_size,
                              hipStream_t stream) {
    const float* x = (const float*)d_in[0];   // (1024,256,7,7)
    const float* W = (const float*)d_in[1];   // (128,3,3,512)
    float* out = (float*)d_out;               // (1024,512,7,7)
    __bf16* Wp = (__bf16*)d_ws;               // 73728*8 bf16 = 1.18 MB
    (void)in_sizes; (void)n_in; (void)out_size; (void)ws_size;

    hipFuncSetAttribute(reinterpret_cast<const void*>(conv_mfma),
                        hipFuncAttributeMaxDynamicSharedMemorySize, 90112);

    hipLaunchKernelGGL(pack_w, dim3(288), dim3(256), 0, stream, W, Wp);
    hipLaunchKernelGGL(conv_mfma, dim3(512), dim3(512), 90112, stream, x, Wp, out);
}

// Round 13
// 92.601 us; speedup vs baseline: 1.1222x; 1.0211x over previous
//
#include <hip/hip_runtime.h>

typedef __attribute__((ext_vector_type(8)))  __bf16 bvec8;
typedef __attribute__((ext_vector_type(4)))  __bf16 bvec4;
typedef __attribute__((ext_vector_type(16))) float  fvec16;
typedef __attribute__((ext_vector_type(8)))  short  svec8;

// ---- pack W[l][j][k][i] fp32 -> Wp bf16, per-wave-unique 32x32x16 frags ----
// unit u: lane=u&63, f=(u>>6)&3 (am=f&1,h=f>>1), wd=(u>>8)&7, t=u>>11 (0..35)
// content: i = wd*64 + am*32 + (lane&31) ; K = (2t+h)*16 + (lane>>5)*8 + e
__global__ __launch_bounds__(256) void pack_w(const float* __restrict__ W,
                                              __bf16* __restrict__ Wp) {
    int u = blockIdx.x * 256 + threadIdx.x;
    if (u >= 73728) return;                   // 36 t * 8 wd * 4 f * 64 lanes
    int lane = u & 63;
    int f    = (u >> 6) & 3;
    int wd   = (u >> 8) & 7;
    int t    = u >> 11;
    int am = f & 1, h = f >> 1;
    int i  = (wd << 6) + (am << 5) + (lane & 31);
    int K0 = ((2 * t + h) << 4) + ((lane >> 5) << 3);
    bvec8 o;
#pragma unroll
    for (int e = 0; e < 8; ++e) {
        int K  = K0 + e;
        int jk = K >> 7;
        int l  = K & 127;
        int j  = (jk * 11) >> 5;              // jk/3 for jk<9
        int k  = jk - 3 * j;
        o[e] = (__bf16)W[((l * 9 + j * 3 + k) << 9) + i];
    }
    *(bvec8*)&Wp[(size_t)u * 8] = o;
}

// ---- main: block = 2 batches x 512 i x 49 s, 512 thr = 8 waves ----
// wave wd owns i in [wd*64, wd*64+64): am2 x sn2 x bb2 -> acc[2][2][2] (128 AGPR).
// W frags UNIQUE per wave: 4 global b128 loads/step/wave.
// ys dedup (per batch, 78 rows x 128 l), 16B-unit swizzle u^=(row&15); row 77 zeros.
// K-loop: barrier-free; W reg-dbuf dist-2 (aE/aO); bf reg-dbuf dist-1 (bfA/bfB).
// LDS 65024 B (xs reused per batch) -> 2 blocks/CU for cross-block overlap.
__global__ __launch_bounds__(512, 2) void conv_mfma(
    const float* __restrict__ x, const __bf16* __restrict__ Wp,
    float* __restrict__ out)
{
    __shared__ __align__(16) char smem[65024];
    __bf16* xs = (__bf16*)smem;               // 12544 bf16 = 25088 B (per-batch stage)
    __bf16* ys = (__bf16*)(smem + 25088);     // 2 x 78 x 128 bf16 = 39936 B

    const int tid  = threadIdx.x;
    const int lane = tid & 63;
    const int l31  = lane & 31;
    const int ls5  = lane >> 5;
    const int wd   = tid >> 6;                // wave 0..7: i-slice [wd*64, wd*64+64)
    const int b0   = blockIdx.x * 2;

    const float* xb  = x + (size_t)b0 * 12544;
    const char*  WpB = (const char*)Wp;
    const int wbase  = wd * 4096 + lane * 16; // wave's byte base within a 32 KB tile

    // ---- W prologue: tiles 0,1 into regs (land during build) ----
    bvec8 aE[2][2], aO[2][2];
#pragma unroll
    for (int am = 0; am < 2; ++am)
#pragma unroll
        for (int h = 0; h < 2; ++h) {
            aE[am][h] = *(const bvec8*)(WpB + wbase + ((h * 2 + am) << 10));
            aO[am][h] = *(const bvec8*)(WpB + 32768 + wbase + ((h * 2 + am) << 10));
        }

    // ---- build: per batch sequentially (xs region reused) ----
    for (int bb = 0; bb < 2; ++bb) {
        // stage x[b0+bb] f32 -> xs bf16, float4-vectorized coalesced
        for (int it = 0; it < 7; ++it) {
            int e4 = it * 512 + tid;
            if (e4 < 3136) {
                const float4 v = ((const float4*)(xb + bb * 12544))[e4];
                bvec4 pk = { (__bf16)v.x, (__bf16)v.y, (__bf16)v.z, (__bf16)v.w };
                *(bvec4*)&xs[e4 * 4] = pk;
            }
        }
        __syncthreads();
        // write-once dedup ys rows (1248 units)
        for (int it = 0; it < 3; ++it) {
            int up = it * 512 + tid;
            if (up < 1248) {
                int row  = up >> 4;
                int useg = up & 15;
                int l0   = useg * 8;
                bvec8 ov;
                if (row == 77) {
                    ov = __builtin_bit_cast(bvec8, (svec8)0);
                } else if (row < 63) {
                    int t = row / 7, w = row - t * 7;
                    int tb = t + 5; if (tb >= 7) tb -= 7;
                    int cB = tb * 7 + w;
                    bool mA = (t >= 1) && (t <= 7);
                    int cA = mA ? (t - 1) * 7 + w : 0;
#pragma unroll
                    for (int d = 0; d < 8; ++d) {
                        float fa = mA ? (float)xs[(l0 + d) * 49 + cA] : 0.f;
                        float fb = (float)xs[(128 + l0 + d) * 49 + cB];
                        ov[d] = (__bf16)(fa + fb);
                    }
                } else if (row < 70) {
                    int w = row - 63;
#pragma unroll
                    for (int d = 0; d < 8; ++d) ov[d] = xs[(l0 + d) * 49 + w];
                } else {
                    int w = row - 70;
#pragma unroll
                    for (int d = 0; d < 8; ++d) ov[d] = xs[(l0 + d) * 49 + 7 + w];
                }
                *(bvec8*)&ys[((bb * 78 + row) << 7) + ((useg ^ (row & 15)) << 3)] = ov;
            }
        }
        __syncthreads();   // ys[bb] done; xs free for next batch (last: pre-K barrier)
    }

    // ---- per-lane column geometry: s = sn*32 + l31, both s-tiles per wave ----
    int nq[2], oo[2];
#pragma unroll
    for (int sn = 0; sn < 2; ++sn) {
        int s = sn * 32 + l31;
        int sc = (s < 49) ? s : 48;
        nq[sn] = sc / 7;
        oo[sn] = sc - nq[sn] * 7;
    }

    fvec16 acc[2][2][2];
#pragma unroll
    for (int am = 0; am < 2; ++am)
#pragma unroll
        for (int sn = 0; sn < 2; ++sn)
#pragma unroll
            for (int bb = 0; bb < 2; ++bb)
#pragma unroll
                for (int r = 0; r < 16; ++r) acc[am][sn][bb][r] = 0.f;

#define GEO(JK, ROWE, RX) {                                                   \
        int j_ = ((JK) * 11) >> 5; int k_ = (JK) - 3 * j_;                    \
        _Pragma("unroll")                                                     \
        for (int sn_ = 0; sn_ < 2; ++sn_) {                                   \
            int tw_ = oo[sn_] + k_ + 5; int w_ = tw_ >= 7 ? tw_ - 7 : tw_;    \
            int row_ = (nq[sn_] + j_) * 7 + w_;                               \
            if (nq[sn_] == 1 && j_ == 0) row_ = 63 + w_;                      \
            if (nq[sn_] == 0 && j_ == 2) row_ = 70 + w_;                      \
            if ((k_ == 0 && oo[sn_] == 0) || (k_ == 2 && oo[sn_] == 6))       \
                row_ = 77;                                                    \
            ROWE[sn_] = row_ << 7; RX[sn_] = row_ & 15; } }

#define READF(DST, P, ROWE, RX) {                                             \
        _Pragma("unroll")                                                     \
        for (int sn_ = 0; sn_ < 2; ++sn_)                                     \
        _Pragma("unroll")                                                     \
        for (int h_ = 0; h_ < 2; ++h_) {                                      \
            int u_ = ((P) * 4 + h_ * 2 + ls5) ^ RX[sn_];                      \
            DST[sn_][0][h_] = *(const bvec8*)&ys[ROWE[sn_] + (u_ << 3)];      \
            DST[sn_][1][h_] = *(const bvec8*)&ys[9984 + ROWE[sn_] + (u_ << 3)]; } }

#define MFMA16(AW, BF) {                                                      \
        __builtin_amdgcn_s_setprio(1);                                        \
        _Pragma("unroll")                                                     \
        for (int h_ = 0; h_ < 2; ++h_)                                        \
        _Pragma("unroll")                                                     \
        for (int am_ = 0; am_ < 2; ++am_)                                     \
        _Pragma("unroll")                                                     \
        for (int sn_ = 0; sn_ < 2; ++sn_)                                     \
        _Pragma("unroll")                                                     \
        for (int bb_ = 0; bb_ < 2; ++bb_)                                     \
            acc[am_][sn_][bb_] = __builtin_amdgcn_mfma_f32_32x32x16_bf16(     \
                AW[am_][h_], BF[sn_][bb_][h_], acc[am_][sn_][bb_], 0, 0, 0);  \
        __builtin_amdgcn_s_setprio(0); }

#define PREFW(AW, TT) {                                                       \
        const char* gp_ = WpB + ((size_t)(TT) << 15) + wbase;                 \
        _Pragma("unroll")                                                     \
        for (int am_ = 0; am_ < 2; ++am_)                                     \
        _Pragma("unroll")                                                     \
        for (int h_ = 0; h_ < 2; ++h_)                                        \
            AW[am_][h_] = *(const bvec8*)(gp_ + ((h_ * 2 + am_) << 10)); }

    // ---- K-loop: 9 jk x 4 steps, barrier-free, dual reg-dbuf ----
    int rowE[2], rx[2], rowEn[2], rxn[2];
    GEO(0, rowE, rx);
    bvec8 bfA[2][2][2], bfB[2][2][2];
    READF(bfA, 0, rowE, rx);

    for (int jk = 0; jk < 9; ++jk) {
        const int t0 = jk * 4;
        // p0: aE holds tile t0
        READF(bfB, 1, rowE, rx);
        MFMA16(aE, bfA);
        PREFW(aE, t0 + 2);
        // p1
        READF(bfA, 2, rowE, rx);
        MFMA16(aO, bfB);
        PREFW(aO, t0 + 3);
        // p2
        { int jn = jk < 8 ? jk + 1 : 8; GEO(jn, rowEn, rxn); }
        READF(bfB, 3, rowE, rx);
        MFMA16(aE, bfA);
        if (jk < 8) PREFW(aE, t0 + 4);
        // p3: read p0 of next jk with next geometry
        READF(bfA, 0, rowEn, rxn);
        MFMA16(aO, bfB);
        if (jk < 8) PREFW(aO, t0 + 5);
#pragma unroll
        for (int sn = 0; sn < 2; ++sn) { rowE[sn] = rowEn[sn]; rx[sn] = rxn[sn]; }
    }

#undef GEO
#undef READF
#undef MFMA16
#undef PREFW

    // ---- epilogue: direct stores. D row=(r&3)+8*(r>>2)+4*ls5 -> i ; col=l31 -> s ----
#pragma unroll
    for (int am = 0; am < 2; ++am) {
        const int i0 = wd * 64 + am * 32 + 4 * ls5;
#pragma unroll
        for (int sn = 0; sn < 2; ++sn) {
            if (sn == 1 && l31 >= 17) continue;   // s >= 49
            const int s = sn * 32 + l31;
#pragma unroll
            for (int bb = 0; bb < 2; ++bb) {
                const size_t ob = (size_t)(b0 + bb) * 25088;
#pragma unroll
                for (int r = 0; r < 16; ++r) {
                    int i = i0 + (r & 3) + 8 * (r >> 2);
                    out[ob + (size_t)i * 49 + s] = acc[am][sn][bb][r];
                }
            }
        }
    }
}

extern "C" void kernel_launch(void* const* d_in, const int* in_sizes, int n_in,
                              void* d_out, int out_size, void* d_ws, size_t ws_size,
                              hipStream_t stream) {
    const float* x = (const float*)d_in[0];   // (1024,256,7,7)
    const float* W = (const float*)d_in[1];   // (128,3,3,512)
    float* out = (float*)d_out;               // (1024,512,7,7)
    __bf16* Wp = (__bf16*)d_ws;               // 73728*8 bf16 = 1.18 MB
    (void)in_sizes; (void)n_in; (void)out_size; (void)ws_size;

    hipLaunchKernelGGL(pack_w, dim3(288), dim3(256), 0, stream, W, Wp);
    hipLaunchKernelGGL(conv_mfma, dim3(512), dim3(512), 0, stream, x, Wp, out);
}

// Round 14
// 90.081 us; speedup vs baseline: 1.1536x; 1.0280x over previous
//
#include <hip/hip_runtime.h>

typedef __attribute__((ext_vector_type(8)))  __bf16 bvec8;
typedef __attribute__((ext_vector_type(4)))  __bf16 bvec4;
typedef __attribute__((ext_vector_type(16))) float  fvec16;
typedef __attribute__((ext_vector_type(8)))  short  svec8;

// ---- pack W[l][j][k][i] fp32 -> Wp bf16, per-WAVE-SLICE (32 i) frags ----
// unit u: lane=u&63, h=(u>>6)&1, it=(u>>7)&15, t=u>>11 (0..35)
// content: i = it*32 + (lane&31) ; K = (2t+h)*16 + (lane>>5)*8 + e
__global__ __launch_bounds__(256) void pack_w(const float* __restrict__ W,
                                              __bf16* __restrict__ Wp) {
    int u = blockIdx.x * 256 + threadIdx.x;
    if (u >= 73728) return;                   // 36 t * 16 it * 2 h * 64 lanes
    int lane = u & 63;
    int h    = (u >> 6) & 1;
    int it   = (u >> 7) & 15;
    int t    = u >> 11;
    int i  = (it << 5) + (lane & 31);
    int K0 = ((2 * t + h) << 4) + ((lane >> 5) << 3);
    bvec8 o;
#pragma unroll
    for (int e = 0; e < 8; ++e) {
        int K  = K0 + e;
        int jk = K >> 7;
        int l  = K & 127;
        int j  = (jk * 11) >> 5;              // jk/3 for jk<9
        int k  = jk - 3 * j;
        o[e] = (__bf16)W[((l * 9 + j * 3 + k) << 9) + i];
    }
    *(bvec8*)&Wp[(size_t)u * 8] = o;
}

// ---- main: block = 2 batches x 512 i x 49 s, 1024 thr = 16 waves ----
// wave wd owns i-slice [wd*32, wd*32+32): sn2 x bb2 -> acc[2][2] (64 AGPR).
// W frags unique per wave: 2 global b128 loads/step (dist-2 reg dbuf aE/aO).
// ys dedup (per batch, 78 rows x 128 l), 16B-unit swizzle u^=(row&15); row 77 zeros.
// 16 waves/CU (4/SIMD) via __launch_bounds__(1024,4): <=128 unified regs/wave.
__global__ __launch_bounds__(1024, 4) void conv_mfma(
    const float* __restrict__ x, const __bf16* __restrict__ Wp,
    float* __restrict__ out)
{
    __shared__ __align__(16) char smem[65024];
    __bf16* xs = (__bf16*)smem;               // 12544 bf16 = 25088 B (per-batch stage)
    __bf16* ys = (__bf16*)(smem + 25088);     // 2 x 78 x 128 bf16 = 39936 B

    const int tid  = threadIdx.x;
    const int lane = tid & 63;
    const int l31  = lane & 31;
    const int ls5  = lane >> 5;
    const int wd   = tid >> 6;                // wave 0..15: i-slice [wd*32, wd*32+32)
    const int b0   = blockIdx.x * 2;

    const float* xb  = x + (size_t)b0 * 12544;
    const char*  WpB = (const char*)Wp;
    const int wbase  = wd * 2048 + lane * 16; // wave's byte base within a 32 KB tile

    // ---- W prologue: tiles 0,1 into regs (land during build) ----
    bvec8 aE[2], aO[2];
#pragma unroll
    for (int h = 0; h < 2; ++h) {
        aE[h] = *(const bvec8*)(WpB + wbase + (h << 10));
        aO[h] = *(const bvec8*)(WpB + 32768 + wbase + (h << 10));
    }

    // ---- build: per batch sequentially (xs region reused) ----
    for (int bb = 0; bb < 2; ++bb) {
        // stage x[b0+bb] f32 -> xs bf16, float4-vectorized coalesced
        for (int it = 0; it < 4; ++it) {
            int e4 = it * 1024 + tid;
            if (e4 < 3136) {
                const float4 v = ((const float4*)(xb + bb * 12544))[e4];
                bvec4 pk = { (__bf16)v.x, (__bf16)v.y, (__bf16)v.z, (__bf16)v.w };
                *(bvec4*)&xs[e4 * 4] = pk;
            }
        }
        __syncthreads();
        // write-once dedup ys rows (1248 units)
        for (int it = 0; it < 2; ++it) {
            int up = it * 1024 + tid;
            if (up < 1248) {
                int row  = up >> 4;
                int useg = up & 15;
                int l0   = useg * 8;
                bvec8 ov;
                if (row == 77) {
                    ov = __builtin_bit_cast(bvec8, (svec8)0);
                } else if (row < 63) {
                    int t = row / 7, w = row - t * 7;
                    int tb = t + 5; if (tb >= 7) tb -= 7;
                    int cB = tb * 7 + w;
                    bool mA = (t >= 1) && (t <= 7);
                    int cA = mA ? (t - 1) * 7 + w : 0;
#pragma unroll
                    for (int d = 0; d < 8; ++d) {
                        float fa = mA ? (float)xs[(l0 + d) * 49 + cA] : 0.f;
                        float fb = (float)xs[(128 + l0 + d) * 49 + cB];
                        ov[d] = (__bf16)(fa + fb);
                    }
                } else if (row < 70) {
                    int w = row - 63;
#pragma unroll
                    for (int d = 0; d < 8; ++d) ov[d] = xs[(l0 + d) * 49 + w];
                } else {
                    int w = row - 70;
#pragma unroll
                    for (int d = 0; d < 8; ++d) ov[d] = xs[(l0 + d) * 49 + 7 + w];
                }
                *(bvec8*)&ys[((bb * 78 + row) << 7) + ((useg ^ (row & 15)) << 3)] = ov;
            }
        }
        __syncthreads();   // ys[bb] done; xs free for next batch (last: pre-K barrier)
    }

    // ---- per-lane column geometry: s = sn*32 + l31, both s-tiles per wave ----
    int nq[2], oo[2];
#pragma unroll
    for (int sn = 0; sn < 2; ++sn) {
        int s = sn * 32 + l31;
        int sc = (s < 49) ? s : 48;
        nq[sn] = sc / 7;
        oo[sn] = sc - nq[sn] * 7;
    }

    fvec16 acc[2][2];
#pragma unroll
    for (int sn = 0; sn < 2; ++sn)
#pragma unroll
        for (int bb = 0; bb < 2; ++bb)
#pragma unroll
            for (int r = 0; r < 16; ++r) acc[sn][bb][r] = 0.f;

#define GEO(JK, ROWE, RX) {                                                   \
        int j_ = ((JK) * 11) >> 5; int k_ = (JK) - 3 * j_;                    \
        _Pragma("unroll")                                                     \
        for (int sn_ = 0; sn_ < 2; ++sn_) {                                   \
            int tw_ = oo[sn_] + k_ + 5; int w_ = tw_ >= 7 ? tw_ - 7 : tw_;    \
            int row_ = (nq[sn_] + j_) * 7 + w_;                               \
            if (nq[sn_] == 1 && j_ == 0) row_ = 63 + w_;                      \
            if (nq[sn_] == 0 && j_ == 2) row_ = 70 + w_;                      \
            if ((k_ == 0 && oo[sn_] == 0) || (k_ == 2 && oo[sn_] == 6))       \
                row_ = 77;                                                    \
            ROWE[sn_] = row_ << 7; RX[sn_] = row_ & 15; } }

    // per p-step: for h: {4 bf reads; 4 MFMA}; then prefetch W tile t+2.
#define STEP(P, AW, TNEXT, DOPF) {                                            \
        bvec8 bf[2][2];                                                       \
        __builtin_amdgcn_s_setprio(1);                                        \
        _Pragma("unroll")                                                     \
        for (int h_ = 0; h_ < 2; ++h_) {                                      \
            _Pragma("unroll")                                                 \
            for (int sn_ = 0; sn_ < 2; ++sn_) {                               \
                int u_ = ((P) * 4 + h_ * 2 + ls5) ^ rx[sn_];                  \
                bf[sn_][0] = *(const bvec8*)&ys[rowE[sn_] + (u_ << 3)];       \
                bf[sn_][1] = *(const bvec8*)&ys[9984 + rowE[sn_] + (u_ << 3)];\
            }                                                                 \
            _Pragma("unroll")                                                 \
            for (int sn_ = 0; sn_ < 2; ++sn_)                                 \
            _Pragma("unroll")                                                 \
            for (int bb_ = 0; bb_ < 2; ++bb_)                                 \
                acc[sn_][bb_] = __builtin_amdgcn_mfma_f32_32x32x16_bf16(      \
                    AW[h_], bf[sn_][bb_], acc[sn_][bb_], 0, 0, 0);            \
        }                                                                     \
        __builtin_amdgcn_s_setprio(0);                                        \
        if (DOPF) {                                                           \
            const char* gp_ = WpB + ((size_t)(TNEXT) << 15) + wbase;          \
            AW[0] = *(const bvec8*)(gp_);                                     \
            AW[1] = *(const bvec8*)(gp_ + 1024);                              \
        } }

    // ---- K-loop: 9 jk x 4 steps, barrier-free ----
    int rowE[2], rx[2];
    for (int jk = 0; jk < 9; ++jk) {
        const int t0 = jk * 4;
        GEO(jk, rowE, rx);
        STEP(0, aE, t0 + 2, true)
        STEP(1, aO, t0 + 3, true)
        STEP(2, aE, t0 + 4, (jk < 8))
        STEP(3, aO, t0 + 5, (jk < 8))
    }

#undef GEO
#undef STEP

    // ---- epilogue: direct stores. D row=(r&3)+8*(r>>2)+4*ls5 -> i ; col=l31 -> s ----
    const int i0 = wd * 32 + 4 * ls5;
#pragma unroll
    for (int sn = 0; sn < 2; ++sn) {
        if (sn == 1 && l31 >= 17) continue;   // s >= 49
        const int s = sn * 32 + l31;
#pragma unroll
        for (int bb = 0; bb < 2; ++bb) {
            const size_t ob = (size_t)(b0 + bb) * 25088;
#pragma unroll
            for (int r = 0; r < 16; ++r) {
                int i = i0 + (r & 3) + 8 * (r >> 2);
                out[ob + (size_t)i * 49 + s] = acc[sn][bb][r];
            }
        }
    }
}

extern "C" void kernel_launch(void* const* d_in, const int* in_sizes, int n_in,
                              void* d_out, int out_size, void* d_ws, size_t ws_size,
                              hipStream_t stream) {
    const float* x = (const float*)d_in[0];   // (1024,256,7,7)
    const float* W = (const float*)d_in[1];   // (128,3,3,512)
    float* out = (float*)d_out;               // (1024,512,7,7)
    __bf16* Wp = (__bf16*)d_ws;               // 73728*8 bf16 = 1.18 MB
    (void)in_sizes; (void)n_in; (void)out_size; (void)ws_size;

    hipLaunchKernelGGL(pack_w, dim3(288), dim3(256), 0, stream, W, Wp);
    hipLaunchKernelGGL(conv_mfma, dim3(512), dim3(1024), 0, stream, x, Wp, out);
}